// Round 12
// baseline (265.152 us; speedup 1.0000x reference)
//
#include <hip/hip_runtime.h>
#include <stdint.h>

#define B_DIM 256
#define S_DIM 16384
#define HALF_S 8192
#define D_DIM 113          // 7*16+1
#define NTH 1024
#define NIT 32             // HALF_S / 256 rows-per-iteration
#define HDW 1024           // hist dwords per feature (2048 bins, u16-packed)

__device__ __forceinline__ uint32_t enc_key(float v) {
    uint32_t u = __float_as_uint(v);
    uint32_t m = (uint32_t)((int32_t)u >> 31) | 0x80000000u;
    return u ^ m;
}
__device__ __forceinline__ float dec_key(uint32_t k) {
    uint32_t u = (k & 0x80000000u) ? (k ^ 0x80000000u) : ~k;
    return __uint_as_float(u);
}
__device__ __forceinline__ uint32_t umn(uint32_t a, uint32_t b) { return a < b ? a : b; }
__device__ __forceinline__ uint32_t umx(uint32_t a, uint32_t b) { return a > b ? a : b; }

// ---------------------------------------------------------------------------
// K1: the R9 champion kernel (114.8us wall), byte-exact, with ONE change:
// #pragma unroll 4 -> 8 on the dense loop. Rationale: all pipes <40% busy at
// 86% occupancy -> latency-hiding is marginal (8 waves/SIMD x ~80 busy
// cycles/iter ~ load latency). Deeper unroll doubles in-flight loads per
// wave; VGPR headroom (32 used / 64 allowed) absorbs it.
// Block (b, shalf): rows [shalf*8192,+8192), all 16 features, dense 64B
// lines. One pass: sum/ssq/key-min/max/count + 11-bit u16-packed histogram.
// Detect (mask dtype bool-1B vs int32-4B) inline per block: distributed
// across 512 blocks (standalone 1-block detect cost ~20us in R11 -- never
// again).
// ---------------------------------------------------------------------------
__global__ __launch_bounds__(NTH, 8) void hist_kernel(
        const float* __restrict__ in, const unsigned char* __restrict__ mb,
        uint32_t* __restrict__ hws, float* __restrict__ psum,
        float* __restrict__ pssq, uint32_t* __restrict__ pkmin,
        uint32_t* __restrict__ pkmax, uint32_t* __restrict__ pn) {
    __shared__ uint32_t uni[16384];          // 64KB: hist[16 f][1024 dw]
    __shared__ float w_sum[16][16], w_ssq[16][16];
    __shared__ uint32_t w_kmin[16][16], w_kmax[16][16], w_cnt[16];
    __shared__ uint32_t s_det;

    const int t = threadIdx.x;
    const int b = blockIdx.x & 255;
    const int sh = blockIdx.x >> 8;
    const int c = t & 3;                     // feature quad c*4..c*4+3
    const float INFV = __uint_as_float(0x7F800000u);

    // clear hist + detect mask dtype (bool-1B vs int32-4B; int32 0/1 data has
    // all non-LSB bytes zero on any window)
    #pragma unroll
    for (int i = 0; i < 16; ++i) uni[i * NTH + t] = 0u;
    if (t == 0) s_det = 0u;
    {
        const uint32_t* mw32 = reinterpret_cast<const uint32_t*>(mb);
        uint32_t x = mw32[b * 1024 + t] & 0xFFFFFF00u;
        unsigned long long any = __ballot(x != 0);
        if ((t & 63) == 0 && any) atomicOr(&s_det, 1u);
    }
    __syncthreads();
    const size_t mstride = s_det ? (size_t)1 : (size_t)4;
    const unsigned char* __restrict__ mrow = mb + (size_t)b * S_DIM * mstride;

    const float4* __restrict__ base4 = reinterpret_cast<const float4*>(in)
        + (size_t)b * S_DIM * 4;

    // dense pass: stats + hist
    float sumv[4] = {0.f, 0.f, 0.f, 0.f}, ssqv[4] = {0.f, 0.f, 0.f, 0.f};
    uint32_t kmn[4] = {~0u, ~0u, ~0u, ~0u}, kmx[4] = {0u, 0u, 0u, 0u};
    uint32_t cnt = 0;
    #pragma unroll 8
    for (int i = 0; i < NIT; ++i) {
        int s = sh * HALF_S + i * 256 + (t >> 2);
        float4 v = base4[(size_t)s * 4 + c];
        uint32_t m = mrow[(size_t)s * mstride] ? 1u : 0u;
        cnt += (c == 0) ? m : 0u;            // each row counted once (quad-0 lane)
        float vv[4] = {v.x, v.y, v.z, v.w};
        #pragma unroll
        for (int q = 0; q < 4; ++q) {
            float vh = m ? vv[q] : INFV;
            uint32_t key = enc_key(vh);
            kmn[q] = umn(kmn[q], key);
            kmx[q] = umx(kmx[q], m ? key : 0u);
            float vs = m ? vv[q] : 0.f;
            sumv[q] += vs;
            ssqv[q] = fmaf(vs, vs, ssqv[q]);
            if (m) {
                uint32_t bin = key >> 21;    // 11-bit
                atomicAdd(&uni[((uint32_t)c * 4 + q) * HDW + (bin >> 1)],
                          (bin & 1) ? 65536u : 1u);
            }
        }
    }

    // quad-class-preserving shuffle reduction (offsets >= 4)
    #pragma unroll
    for (int off = 32; off >= 4; off >>= 1) {
        #pragma unroll
        for (int q = 0; q < 4; ++q) {
            sumv[q] += __shfl_down(sumv[q], off);
            ssqv[q] += __shfl_down(ssqv[q], off);
            kmn[q] = umn(kmn[q], __shfl_down(kmn[q], off));
            kmx[q] = umx(kmx[q], __shfl_down(kmx[q], off));
        }
        cnt += __shfl_down(cnt, off);
    }
    {
        int w = t >> 6, lane = t & 63;
        if (lane < 4) {
            #pragma unroll
            for (int q = 0; q < 4; ++q) {
                w_sum[w][lane * 4 + q] = sumv[q];
                w_ssq[w][lane * 4 + q] = ssqv[q];
                w_kmin[w][lane * 4 + q] = kmn[q];
                w_kmax[w][lane * 4 + q] = kmx[q];
            }
            if (lane == 0) w_cnt[w] = cnt;
        }
    }
    __syncthreads();                          // also fences all hist atomics

    // write partial stats + partial hist to ws
    if (t < 16) {
        float s0 = 0.f, q0 = 0.f;
        uint32_t mnv = ~0u, mxv = 0u;
        for (int w = 0; w < 16; ++w) {
            s0 += w_sum[w][t]; q0 += w_ssq[w][t];
            mnv = umn(mnv, w_kmin[w][t]); mxv = umx(mxv, w_kmax[w][t]);
        }
        int bid = blockIdx.x;
        psum[bid * 16 + t] = s0; pssq[bid * 16 + t] = q0;
        pkmin[bid * 16 + t] = mnv; pkmax[bid * 16 + t] = mxv;
        if (t == 0) {
            uint32_t nn = 0;
            for (int w = 0; w < 16; ++w) nn += w_cnt[w];
            pn[bid] = nn;
        }
    }
    uint32_t* hb = hws + (size_t)blockIdx.x * 16384;
    #pragma unroll
    for (int i = 0; i < 16; ++i) hb[i * NTH + t] = uni[i * NTH + t];
}

// ---------------------------------------------------------------------------
// K2: EXACT R9 final kernel. Merge the two halves' hists (packed u16 add is
// carry-safe: per-half bin count <= 8192), merge stats, locate each rank's
// bin (wave per feature: chunk sums + wave scan + binary search + bin walk),
// interpolate within the bin, build pooled[113] in LDS, run the fused
// 113->16->4->1 MLP on wave 0. Empty row -> pooled = zeros -> MLP(0).
// ---------------------------------------------------------------------------
__global__ __launch_bounds__(NTH, 4) void final_kernel(
        const uint32_t* __restrict__ hws, const float* __restrict__ psum,
        const float* __restrict__ pssq, const uint32_t* __restrict__ pkmin,
        const uint32_t* __restrict__ pkmax, const uint32_t* __restrict__ pn,
        const float* __restrict__ W1, const float* __restrict__ b1,
        const float* __restrict__ W2, const float* __restrict__ b2,
        const float* __restrict__ W3, const float* __restrict__ b3,
        float* __restrict__ out) {
    __shared__ uint32_t uni[16384];          // merged hist
    __shared__ uint32_t chunks[16][64];
    __shared__ float pool[128];
    __shared__ uint32_t s_nsh;

    const int t = threadIdx.x;
    const int b = blockIdx.x;

    const uint32_t* h0 = hws + (size_t)b * 16384;
    const uint32_t* h1 = hws + (size_t)(b + 256) * 16384;
    #pragma unroll
    for (int i = 0; i < 16; ++i) uni[i * NTH + t] = h0[i * NTH + t] + h1[i * NTH + t];
    if (t == 0) s_nsh = pn[b] + pn[b + 256];
    if (t < 128) pool[t] = 0.f;
    __syncthreads();
    const uint32_t n = s_nsh;

    if (n != 0) {
        // merged exact stats -> pool
        if (t < 16) {
            float s0 = psum[b * 16 + t] + psum[(b + 256) * 16 + t];
            float q0 = pssq[b * 16 + t] + pssq[(b + 256) * 16 + t];
            uint32_t mnv = umn(pkmin[b * 16 + t], pkmin[(b + 256) * 16 + t]);
            uint32_t mxv = umx(pkmax[b * 16 + t], pkmax[(b + 256) * 16 + t]);
            float nf = (float)n;
            float mean = s0 / nf;
            float varn = q0 - s0 * s0 / nf;
            float denom = (float)(n >= 2 ? n - 1 : 1);
            float stdv = sqrtf(fmaxf(varn, 0.f) / denom);
            if (t == 0) pool[0] = nf;
            pool[1 + t] = mean;
            pool[33 + t] = dec_key(mnv);
            pool[49 + t] = dec_key(mxv);
            pool[65 + t] = stdv;
        }
        // chunk sums (64 chunks x 32 bins, rotated reads) + wave scan; wave = feature
        {
            int f = t >> 6, l = t & 63;
            uint32_t csum = 0;
            int base = f * HDW + l * 16;
            #pragma unroll
            for (int k = 0; k < 16; ++k) {
                uint32_t w = uni[base + ((k + l) & 15)];
                csum += (w & 0xFFFFu) + (w >> 16);
            }
            #pragma unroll
            for (int off = 1; off < 64; off <<= 1) {
                uint32_t o = __shfl_up(csum, off);
                if (l >= off) csum += o;
            }
            chunks[f][l] = csum;
        }
        __syncthreads();
        // locate + within-bin interpolation: lanes 0..2 of each wave = q25/q50/q75
        {
            int f = t >> 6, l = t & 63;
            if (l < 3) {
                float pos = 0.25f * (float)(l + 1) * (float)(n - 1);
                uint32_t r = (uint32_t)pos;  // floor
                int lo = 0, hi = 63;
                while (lo < hi) {            // first chunk with inclusive-sum > r
                    int mid = (lo + hi) >> 1;
                    if (chunks[f][mid] > r) hi = mid; else lo = mid + 1;
                }
                uint32_t acc = lo ? chunks[f][lo - 1] : 0u;
                uint32_t bin = (uint32_t)lo * 32u;
                for (;;) {
                    uint32_t w = uni[f * HDW + (bin >> 1)];
                    uint32_t h = (w >> ((bin & 1) * 16)) & 0xFFFFu;
                    if (acc + h > r) {
                        float pib = pos - (float)acc;        // in [0, h)
                        float vlo = dec_key(bin << 21);
                        float vhi = dec_key(umn((bin + 1) << 21, 0xFF7FFFFFu));
                        float qv = vlo + ((pib + 0.5f) / (float)h) * (vhi - vlo);
                        pool[(l == 0 ? 81 : (l == 1 ? 17 : 97)) + f] = qv;
                        break;
                    }
                    acc += h; ++bin;
                }
            }
        }
    }
    __syncthreads();

    // fused MLP on wave 0: 113 -> 16 -> 4 -> 1
    if (t < 64) {
        float h = (t < 16) ? b1[t] : 0.f;
        for (int i = 0; i < D_DIM; ++i) {
            float pv = pool[i];
            if (t < 16) h += pv * W1[i * 16 + t];
        }
        if (t < 16) h = fmaxf(h, 0.f);
        float h2 = (t < 4) ? b2[t] : 0.f;
        #pragma unroll
        for (int j = 0; j < 16; ++j) {
            float hj = __shfl(h, j);
            if (t < 4) h2 += hj * W2[j * 4 + t];
        }
        if (t < 4) h2 = fmaxf(h2, 0.f);
        float o = 0.f;
        #pragma unroll
        for (int j = 0; j < 4; ++j) {
            float hj = __shfl(h2, j);
            o += hj * W3[j];
        }
        if (t == 0) out[b] = o + b3[0];
    }
}

extern "C" void kernel_launch(void* const* d_in, const int* in_sizes, int n_in,
                              void* d_out, int out_size, void* d_ws, size_t ws_size,
                              hipStream_t stream) {
    const float* inputs = (const float*)d_in[0];
    const unsigned char* mask = (const unsigned char*)d_in[1];
    const float* W1 = (const float*)d_in[2];
    const float* b1 = (const float*)d_in[3];
    const float* W2 = (const float*)d_in[4];
    const float* b2 = (const float*)d_in[5];
    const float* W3 = (const float*)d_in[6];
    const float* b3 = (const float*)d_in[7];
    float* out = (float*)d_out;

    // ws layout: hist partials 512*64KB = 32MB, then stats partials
    char* w = (char*)d_ws;
    uint32_t* hws  = (uint32_t*)w;                         // 33,554,432 B
    float*    psum = (float*)   (w + 33554432);            // 512*16*4 = 32KB
    float*    pssq = (float*)   (w + 33554432 + 32768);
    uint32_t* pkmn = (uint32_t*)(w + 33554432 + 65536);
    uint32_t* pkmx = (uint32_t*)(w + 33554432 + 98304);
    uint32_t* pn   = (uint32_t*)(w + 33554432 + 131072);   // 512*4 B

    hist_kernel<<<2 * B_DIM, NTH, 0, stream>>>(inputs, mask, hws, psum, pssq,
                                               pkmn, pkmx, pn);
    final_kernel<<<B_DIM, NTH, 0, stream>>>(hws, psum, pssq, pkmn, pkmx, pn,
                                            W1, b1, W2, b2, W3, b3, out);
}

// Round 13
// 116.485 us; speedup vs baseline: 2.2763x; 2.2763x over previous
//
#include <hip/hip_runtime.h>
#include <stdint.h>

#define B_DIM 256
#define S_DIM 16384
#define HALF_S 8192
#define D_DIM 113          // 7*16+1
#define NTH 1024
#define NIT 32             // HALF_S / 256 rows-per-iteration
#define HDW 1024           // hist dwords per feature (2048 bins, u16-packed)

__device__ __forceinline__ uint32_t enc_key(float v) {
    uint32_t u = __float_as_uint(v);
    uint32_t m = (uint32_t)((int32_t)u >> 31) | 0x80000000u;
    return u ^ m;
}
__device__ __forceinline__ float dec_key(uint32_t k) {
    uint32_t u = (k & 0x80000000u) ? (k ^ 0x80000000u) : ~k;
    return __uint_as_float(u);
}
__device__ __forceinline__ uint32_t umn(uint32_t a, uint32_t b) { return a < b ? a : b; }
__device__ __forceinline__ uint32_t umx(uint32_t a, uint32_t b) { return a > b ? a : b; }

// ---------------------------------------------------------------------------
// K1 (R9 CHAMPION, byte-exact revert -- R10 trims/R11 prologue/R12 unroll-8
// all regressed it; this schedule is a sharp local optimum).
// Block (b, shalf) = batch row b, rows [shalf*8192, +8192), ALL 16 features
// -> every wave-load is 1024 contiguous bytes (16 full 64B lines, 100% line
// utilization). ONE dense pass: stats (sum/ssq/key-min/max/count) + 11-bit
// u16-packed histogram per feature. Partial hist (64KB) + partial stats to
// ws; quantiles are interpolated within the located bin in K2 (bin width
// ~0.125 at the quartiles x ~5e-4 MLP sensitivity = ~1e-4 output error vs
// 0.1775 threshold; measured absmax 0.0).
// LDS 64KB + small -> 2 blocks/CU, 32 waves.
// ---------------------------------------------------------------------------
__global__ __launch_bounds__(NTH, 8) void hist_kernel(
        const float* __restrict__ in, const unsigned char* __restrict__ mb,
        uint32_t* __restrict__ hws, float* __restrict__ psum,
        float* __restrict__ pssq, uint32_t* __restrict__ pkmin,
        uint32_t* __restrict__ pkmax, uint32_t* __restrict__ pn) {
    __shared__ uint32_t uni[16384];          // 64KB: hist[16 f][1024 dw]
    __shared__ float w_sum[16][16], w_ssq[16][16];
    __shared__ uint32_t w_kmin[16][16], w_kmax[16][16], w_cnt[16];
    __shared__ uint32_t s_det;

    const int t = threadIdx.x;
    const int b = blockIdx.x & 255;
    const int sh = blockIdx.x >> 8;
    const int c = t & 3;                     // feature quad c*4..c*4+3
    const float INFV = __uint_as_float(0x7F800000u);

    // clear hist + detect mask dtype (bool-1B vs int32-4B; int32 0/1 data has
    // all non-LSB bytes zero on any window)
    #pragma unroll
    for (int i = 0; i < 16; ++i) uni[i * NTH + t] = 0u;
    if (t == 0) s_det = 0u;
    {
        const uint32_t* mw32 = reinterpret_cast<const uint32_t*>(mb);
        uint32_t x = mw32[b * 1024 + t] & 0xFFFFFF00u;
        unsigned long long any = __ballot(x != 0);
        if ((t & 63) == 0 && any) atomicOr(&s_det, 1u);
    }
    __syncthreads();
    const size_t mstride = s_det ? (size_t)1 : (size_t)4;
    const unsigned char* __restrict__ mrow = mb + (size_t)b * S_DIM * mstride;

    const float4* __restrict__ base4 = reinterpret_cast<const float4*>(in)
        + (size_t)b * S_DIM * 4;

    // dense pass: stats + hist
    float sumv[4] = {0.f, 0.f, 0.f, 0.f}, ssqv[4] = {0.f, 0.f, 0.f, 0.f};
    uint32_t kmn[4] = {~0u, ~0u, ~0u, ~0u}, kmx[4] = {0u, 0u, 0u, 0u};
    uint32_t cnt = 0;
    #pragma unroll 4
    for (int i = 0; i < NIT; ++i) {
        int s = sh * HALF_S + i * 256 + (t >> 2);
        float4 v = base4[(size_t)s * 4 + c];
        uint32_t m = mrow[(size_t)s * mstride] ? 1u : 0u;
        cnt += (c == 0) ? m : 0u;            // each row counted once (quad-0 lane)
        float vv[4] = {v.x, v.y, v.z, v.w};
        #pragma unroll
        for (int q = 0; q < 4; ++q) {
            float vh = m ? vv[q] : INFV;
            uint32_t key = enc_key(vh);
            kmn[q] = umn(kmn[q], key);
            kmx[q] = umx(kmx[q], m ? key : 0u);
            float vs = m ? vv[q] : 0.f;
            sumv[q] += vs;
            ssqv[q] = fmaf(vs, vs, ssqv[q]);
            if (m) {
                uint32_t bin = key >> 21;    // 11-bit
                atomicAdd(&uni[((uint32_t)c * 4 + q) * HDW + (bin >> 1)],
                          (bin & 1) ? 65536u : 1u);
            }
        }
    }

    // quad-class-preserving shuffle reduction (offsets >= 4)
    #pragma unroll
    for (int off = 32; off >= 4; off >>= 1) {
        #pragma unroll
        for (int q = 0; q < 4; ++q) {
            sumv[q] += __shfl_down(sumv[q], off);
            ssqv[q] += __shfl_down(ssqv[q], off);
            kmn[q] = umn(kmn[q], __shfl_down(kmn[q], off));
            kmx[q] = umx(kmx[q], __shfl_down(kmx[q], off));
        }
        cnt += __shfl_down(cnt, off);
    }
    {
        int w = t >> 6, lane = t & 63;
        if (lane < 4) {
            #pragma unroll
            for (int q = 0; q < 4; ++q) {
                w_sum[w][lane * 4 + q] = sumv[q];
                w_ssq[w][lane * 4 + q] = ssqv[q];
                w_kmin[w][lane * 4 + q] = kmn[q];
                w_kmax[w][lane * 4 + q] = kmx[q];
            }
            if (lane == 0) w_cnt[w] = cnt;
        }
    }
    __syncthreads();                          // also fences all hist atomics

    // write partial stats + partial hist to ws
    if (t < 16) {
        float s0 = 0.f, q0 = 0.f;
        uint32_t mnv = ~0u, mxv = 0u;
        for (int w = 0; w < 16; ++w) {
            s0 += w_sum[w][t]; q0 += w_ssq[w][t];
            mnv = umn(mnv, w_kmin[w][t]); mxv = umx(mxv, w_kmax[w][t]);
        }
        int bid = blockIdx.x;
        psum[bid * 16 + t] = s0; pssq[bid * 16 + t] = q0;
        pkmin[bid * 16 + t] = mnv; pkmax[bid * 16 + t] = mxv;
        if (t == 0) {
            uint32_t nn = 0;
            for (int w = 0; w < 16; ++w) nn += w_cnt[w];
            pn[bid] = nn;
        }
    }
    uint32_t* hb = hws + (size_t)blockIdx.x * 16384;
    #pragma unroll
    for (int i = 0; i < 16; ++i) hb[i * NTH + t] = uni[i * NTH + t];
}

// ---------------------------------------------------------------------------
// K2 (R9 champion, byte-exact). Merge the two halves' hists (packed u16 add
// is carry-safe: per-half bin count <= 8192), merge stats, locate each rank's
// bin (wave per feature: chunk sums + wave scan + binary search + bin walk),
// interpolate within the bin, build pooled[113] in LDS, run the fused
// 113->16->4->1 MLP on wave 0. Empty row -> pooled = zeros -> MLP(0).
// ---------------------------------------------------------------------------
__global__ __launch_bounds__(NTH, 4) void final_kernel(
        const uint32_t* __restrict__ hws, const float* __restrict__ psum,
        const float* __restrict__ pssq, const uint32_t* __restrict__ pkmin,
        const uint32_t* __restrict__ pkmax, const uint32_t* __restrict__ pn,
        const float* __restrict__ W1, const float* __restrict__ b1,
        const float* __restrict__ W2, const float* __restrict__ b2,
        const float* __restrict__ W3, const float* __restrict__ b3,
        float* __restrict__ out) {
    __shared__ uint32_t uni[16384];          // merged hist
    __shared__ uint32_t chunks[16][64];
    __shared__ float pool[128];
    __shared__ uint32_t s_nsh;

    const int t = threadIdx.x;
    const int b = blockIdx.x;

    const uint32_t* h0 = hws + (size_t)b * 16384;
    const uint32_t* h1 = hws + (size_t)(b + 256) * 16384;
    #pragma unroll
    for (int i = 0; i < 16; ++i) uni[i * NTH + t] = h0[i * NTH + t] + h1[i * NTH + t];
    if (t == 0) s_nsh = pn[b] + pn[b + 256];
    if (t < 128) pool[t] = 0.f;
    __syncthreads();
    const uint32_t n = s_nsh;

    if (n != 0) {
        // merged exact stats -> pool
        if (t < 16) {
            float s0 = psum[b * 16 + t] + psum[(b + 256) * 16 + t];
            float q0 = pssq[b * 16 + t] + pssq[(b + 256) * 16 + t];
            uint32_t mnv = umn(pkmin[b * 16 + t], pkmin[(b + 256) * 16 + t]);
            uint32_t mxv = umx(pkmax[b * 16 + t], pkmax[(b + 256) * 16 + t]);
            float nf = (float)n;
            float mean = s0 / nf;
            float varn = q0 - s0 * s0 / nf;
            float denom = (float)(n >= 2 ? n - 1 : 1);
            float stdv = sqrtf(fmaxf(varn, 0.f) / denom);
            if (t == 0) pool[0] = nf;
            pool[1 + t] = mean;
            pool[33 + t] = dec_key(mnv);
            pool[49 + t] = dec_key(mxv);
            pool[65 + t] = stdv;
        }
        // chunk sums (64 chunks x 32 bins, rotated reads) + wave scan; wave = feature
        {
            int f = t >> 6, l = t & 63;
            uint32_t csum = 0;
            int base = f * HDW + l * 16;
            #pragma unroll
            for (int k = 0; k < 16; ++k) {
                uint32_t w = uni[base + ((k + l) & 15)];
                csum += (w & 0xFFFFu) + (w >> 16);
            }
            #pragma unroll
            for (int off = 1; off < 64; off <<= 1) {
                uint32_t o = __shfl_up(csum, off);
                if (l >= off) csum += o;
            }
            chunks[f][l] = csum;
        }
        __syncthreads();
        // locate + within-bin interpolation: lanes 0..2 of each wave = q25/q50/q75
        {
            int f = t >> 6, l = t & 63;
            if (l < 3) {
                float pos = 0.25f * (float)(l + 1) * (float)(n - 1);
                uint32_t r = (uint32_t)pos;  // floor
                int lo = 0, hi = 63;
                while (lo < hi) {            // first chunk with inclusive-sum > r
                    int mid = (lo + hi) >> 1;
                    if (chunks[f][mid] > r) hi = mid; else lo = mid + 1;
                }
                uint32_t acc = lo ? chunks[f][lo - 1] : 0u;
                uint32_t bin = (uint32_t)lo * 32u;
                for (;;) {
                    uint32_t w = uni[f * HDW + (bin >> 1)];
                    uint32_t h = (w >> ((bin & 1) * 16)) & 0xFFFFu;
                    if (acc + h > r) {
                        float pib = pos - (float)acc;        // in [0, h)
                        float vlo = dec_key(bin << 21);
                        float vhi = dec_key(umn((bin + 1) << 21, 0xFF7FFFFFu));
                        float qv = vlo + ((pib + 0.5f) / (float)h) * (vhi - vlo);
                        pool[(l == 0 ? 81 : (l == 1 ? 17 : 97)) + f] = qv;
                        break;
                    }
                    acc += h; ++bin;
                }
            }
        }
    }
    __syncthreads();

    // fused MLP on wave 0: 113 -> 16 -> 4 -> 1
    if (t < 64) {
        float h = (t < 16) ? b1[t] : 0.f;
        for (int i = 0; i < D_DIM; ++i) {
            float pv = pool[i];
            if (t < 16) h += pv * W1[i * 16 + t];
        }
        if (t < 16) h = fmaxf(h, 0.f);
        float h2 = (t < 4) ? b2[t] : 0.f;
        #pragma unroll
        for (int j = 0; j < 16; ++j) {
            float hj = __shfl(h, j);
            if (t < 4) h2 += hj * W2[j * 4 + t];
        }
        if (t < 4) h2 = fmaxf(h2, 0.f);
        float o = 0.f;
        #pragma unroll
        for (int j = 0; j < 4; ++j) {
            float hj = __shfl(h2, j);
            o += hj * W3[j];
        }
        if (t == 0) out[b] = o + b3[0];
    }
}

extern "C" void kernel_launch(void* const* d_in, const int* in_sizes, int n_in,
                              void* d_out, int out_size, void* d_ws, size_t ws_size,
                              hipStream_t stream) {
    const float* inputs = (const float*)d_in[0];
    const unsigned char* mask = (const unsigned char*)d_in[1];
    const float* W1 = (const float*)d_in[2];
    const float* b1 = (const float*)d_in[3];
    const float* W2 = (const float*)d_in[4];
    const float* b2 = (const float*)d_in[5];
    const float* W3 = (const float*)d_in[6];
    const float* b3 = (const float*)d_in[7];
    float* out = (float*)d_out;

    // ws layout: hist partials 512*64KB = 32MB, then stats partials
    char* w = (char*)d_ws;
    uint32_t* hws  = (uint32_t*)w;                         // 33,554,432 B
    float*    psum = (float*)   (w + 33554432);            // 512*16*4 = 32KB
    float*    pssq = (float*)   (w + 33554432 + 32768);
    uint32_t* pkmn = (uint32_t*)(w + 33554432 + 65536);
    uint32_t* pkmx = (uint32_t*)(w + 33554432 + 98304);
    uint32_t* pn   = (uint32_t*)(w + 33554432 + 131072);   // 512*4 B

    hist_kernel<<<2 * B_DIM, NTH, 0, stream>>>(inputs, mask, hws, psum, pssq,
                                               pkmn, pkmx, pn);
    final_kernel<<<B_DIM, NTH, 0, stream>>>(hws, psum, pssq, pkmn, pkmx, pn,
                                            W1, b1, W2, b2, W3, b3, out);
}